// Round 17
// baseline (68.132 us; speedup 1.0000x reference)
//
#include <hip/hip_runtime.h>
#include <math.h>

namespace {

constexpr int B_ = 4, N_ = 4, C_ = 64, H_ = 128, W_ = 128;
constexpr int HW_ = H_ * W_;
constexpr int CPB = 4;               // channels per barrier window
constexpr int NWIN = C_ / CPB;       // 16 windows per pass
constexpr int ROWS = 4;              // output rows per block

// out[:, 4] = ref
__global__ __launch_bounds__(256) void copyref_kernel(const float* __restrict__ ref,
                                                      float* __restrict__ out) {
    int t = blockIdx.x * 256 + threadIdx.x;      // one float4 per thread
    int f = t * 4;
    int b = f / (C_ * HW_);
    int within = f - b * (C_ * HW_);
    float4 v = *reinterpret_cast<const float4*>(ref + (size_t)b * C_ * HW_ + within);
    *reinterpret_cast<float4*>(out + (size_t)(b * 5 + N_) * C_ * HW_ + within) = v;
}

__device__ __forceinline__ float2 ld2(const float* p) {
    return *reinterpret_cast<const float2*>(p);
}

// 2 px/thread (aligned float2 globals). Block = 256 threads = 4 rows.
// LDS is SoA (separate x/y float planes): all window reads are stride-4B
// ds_read_b32 across all 32 banks — the float2 (AoS) layout of r16 was a
// stride-8B access using only even banks (3.17M conflicts/dispatch).
// grid = B*N*(H/4) = 512 blocks. CPB=4 channels per barrier, double-buffered.
__global__ __launch_bounds__(256) void localcorr_kernel(const float* __restrict__ nbrs,
                                                        const float* __restrict__ ref,
                                                        float* __restrict__ out) {
    __shared__ float s_x[2 * CPB][6][64];      // [slot][staged row][pair col] .x
    __shared__ float s_y[2 * CPB][6][64];      // .y
    __shared__ float s_nx[6][64];              // norms .x
    __shared__ float s_ny[6][64];              // norms .y

    const int blk = blockIdx.x;          // 0..511
    const int ytile = blk & 31;          // H/ROWS = 32
    const int bi = blk >> 5;
    const int i = bi & 3;
    const int b = bi >> 2;
    const int t = (int)threadIdx.x;
    const int xh = t & 63;               // float2 col 0..63
    const int ry = t >> 6;               // 0..3 == wave id == row in block
    const int x0 = xh * 2;
    const int y0 = ytile * ROWS;
    const int y = y0 + ry;

    // pair indices implementing x-reflect: x0==0 -> left = pair0.y (col 1);
    // x0==126 -> right = pair63.x (col 126)
    const int xlh = (xh == 0) ? 0 : xh - 1;
    const int xrh = (xh == 63) ? 63 : xh + 1;
    // staged rows 0..5 = global rows refl(y0-1), y0..y0+3, refl(y0+4)
    const int gTop = (y0 == 0) ? 1 : y0 - 1;
    const int gBot = (y0 + ROWS == H_) ? H_ - 2 : y0 + ROWS;

    const bool isHalo = (t < 128);       // waves 0,1 (wave-uniform)
    const int haloRow = (t < 64) ? 0 : 5;
    const int haloOff = ((t < 64) ? gTop : gBot) * W_ + x0;

    const float* __restrict__ nb = nbrs + (size_t)(b * N_ + i) * C_ * HW_;
    const float* __restrict__ rp = ref + (size_t)b * C_ * HW_;
    const int offO = y * W_ + x0;

    float d0[9], d1[9];
#pragma unroll
    for (int k = 0; k < 9; ++k) { d0[k] = 0.f; d1[k] = 0.f; }
    float na = 0.f, nb2 = 0.f, r20 = 0.f, r21 = 0.f, hna = 0.f, hnb = 0.f;

    // ---- pass 1: dots + norms + ref2 ----
    float2 cO[CPB], cR[CPB], cH[CPB];
    float2 nO[CPB], nR[CPB], nH[CPB];
#pragma unroll
    for (int u = 0; u < CPB; ++u) {
        const size_t co = (size_t)u * HW_;
        cO[u] = ld2(nb + co + offO);
        cR[u] = ld2(rp + co + offO);
        cH[u] = isHalo ? ld2(nb + co + haloOff) : make_float2(0.f, 0.f);
        nH[u] = make_float2(0.f, 0.f);
    }
#pragma unroll 1
    for (int w = 0; w < NWIN; ++w) {
        const int base = (w & 1) * CPB;
#pragma unroll
        for (int u = 0; u < CPB; ++u) {
            s_x[base + u][ry + 1][xh] = cO[u].x;
            s_y[base + u][ry + 1][xh] = cO[u].y;
            if (isHalo) {
                s_x[base + u][haloRow][xh] = cH[u].x;
                s_y[base + u][haloRow][xh] = cH[u].y;
            }
        }
        __syncthreads();
        if (w + 1 < NWIN) {
#pragma unroll
            for (int u = 0; u < CPB; ++u) {
                const size_t co = (size_t)((w + 1) * CPB + u) * HW_;
                nO[u] = ld2(nb + co + offO);
                nR[u] = ld2(rp + co + offO);
                if (isHalo) nH[u] = ld2(nb + co + haloOff);
            }
        }
#pragma unroll
        for (int u = 0; u < CPB; ++u) {
            const float2 rf = cR[u];
            r20 += rf.x * rf.x; r21 += rf.y * rf.y;
            na += cO[u].x * cO[u].x; nb2 += cO[u].y * cO[u].y;
            if (isHalo) { hna += cH[u].x * cH[u].x; hnb += cH[u].y * cH[u].y; }
#pragma unroll
            for (int wr = 0; wr < 3; ++wr) {
                const int r = ry + wr;
                const float Ly = s_y[base + u][r][xlh];
                float Cx, Cy;
                if (wr == 1) { Cx = cO[u].x; Cy = cO[u].y; }
                else         { Cx = s_x[base + u][r][xh]; Cy = s_y[base + u][r][xh]; }
                const float Rx = s_x[base + u][r][xrh];
                d0[3 * wr + 0] += rf.x * Ly;
                d0[3 * wr + 1] += rf.x * Cx;
                d0[3 * wr + 2] += rf.x * Cy;
                d1[3 * wr + 0] += rf.y * Cx;
                d1[3 * wr + 1] += rf.y * Cy;
                d1[3 * wr + 2] += rf.y * Rx;
            }
        }
#pragma unroll
        for (int u = 0; u < CPB; ++u) { cO[u] = nO[u]; cR[u] = nR[u]; cH[u] = nH[u]; }
    }

    // ---- share norms (SoA), softmax for both pixels ----
    s_nx[ry + 1][xh] = na;
    s_ny[ry + 1][xh] = nb2;
    if (isHalo) { s_nx[haloRow][xh] = hna; s_ny[haloRow][xh] = hnb; }
    __syncthreads();

    float nk0[9], nk1[9];
#pragma unroll
    for (int wr = 0; wr < 3; ++wr) {
        const int r = ry + wr;
        const float Ly = s_ny[r][xlh];
        float Cx, Cy;
        if (wr == 1) { Cx = na; Cy = nb2; }
        else         { Cx = s_nx[r][xh]; Cy = s_ny[r][xh]; }
        const float Rx = s_nx[r][xrh];
        nk0[3 * wr + 0] = Ly; nk0[3 * wr + 1] = Cx; nk0[3 * wr + 2] = Cy;
        nk1[3 * wr + 0] = Cx; nk1[3 * wr + 1] = Cy; nk1[3 * wr + 2] = Rx;
    }

    float w0[9], w1[9];
    {
        const float invr = rsqrtf(fmaxf(r20, 1e-24f));
        float iv[9], dd[9];
#pragma unroll
        for (int k = 0; k < 9; ++k) {
            iv[k] = rsqrtf(fmaxf(nk0[k], 1e-24f));
            dd[k] = d0[k] * invr * iv[k];
        }
        float mx = dd[0];
#pragma unroll
        for (int k = 1; k < 9; ++k) mx = fmaxf(mx, dd[k]);
        float ss = 0.f;
#pragma unroll
        for (int k = 0; k < 9; ++k) { dd[k] = __expf(dd[k] - mx); ss += dd[k]; }
        const float is = 1.f / ss;
#pragma unroll
        for (int k = 0; k < 9; ++k) w0[k] = dd[k] * is * iv[k];
    }
    {
        const float invr = rsqrtf(fmaxf(r21, 1e-24f));
        float iv[9], dd[9];
#pragma unroll
        for (int k = 0; k < 9; ++k) {
            iv[k] = rsqrtf(fmaxf(nk1[k], 1e-24f));
            dd[k] = d1[k] * invr * iv[k];
        }
        float mx = dd[0];
#pragma unroll
        for (int k = 1; k < 9; ++k) mx = fmaxf(mx, dd[k]);
        float ss = 0.f;
#pragma unroll
        for (int k = 0; k < 9; ++k) { dd[k] = __expf(dd[k] - mx); ss += dd[k]; }
        const float is = 1.f / ss;
#pragma unroll
        for (int k = 0; k < 9; ++k) w1[k] = dd[k] * is * iv[k];
    }

    // ---- pass 2: aggregate + wdiff + store ----
    const float* __restrict__ pm0 = nbrs + (size_t)(b * N_ + ((i + 1) & 3)) * C_ * HW_;
    const float* __restrict__ pm1 = nbrs + (size_t)(b * N_ + ((i + 2) & 3)) * C_ * HW_;
    const float* __restrict__ pm2 = nbrs + (size_t)(b * N_ + ((i + 3) & 3)) * C_ * HW_;
    float* __restrict__ op = out + (size_t)(b * 5 + i) * C_ * HW_ + offO;

    float2 q0c[CPB], q1c[CPB], q2c[CPB];
    float2 q0n[CPB], q1n[CPB], q2n[CPB];
#pragma unroll
    for (int u = 0; u < CPB; ++u) {
        const size_t co = (size_t)u * HW_;
        cO[u] = ld2(nb + co + offO);
        cH[u] = isHalo ? ld2(nb + co + haloOff) : make_float2(0.f, 0.f);
        q0c[u] = ld2(pm0 + co + offO);
        q1c[u] = ld2(pm1 + co + offO);
        q2c[u] = ld2(pm2 + co + offO);
    }
#pragma unroll 1
    for (int w = 0; w < NWIN; ++w) {
        const int base = (w & 1) * CPB;
#pragma unroll
        for (int u = 0; u < CPB; ++u) {
            s_x[base + u][ry + 1][xh] = cO[u].x;
            s_y[base + u][ry + 1][xh] = cO[u].y;
            if (isHalo) {
                s_x[base + u][haloRow][xh] = cH[u].x;
                s_y[base + u][haloRow][xh] = cH[u].y;
            }
        }
        __syncthreads();
        if (w + 1 < NWIN) {
#pragma unroll
            for (int u = 0; u < CPB; ++u) {
                const size_t co = (size_t)((w + 1) * CPB + u) * HW_;
                nO[u] = ld2(nb + co + offO);
                if (isHalo) nH[u] = ld2(nb + co + haloOff);
                q0n[u] = ld2(pm0 + co + offO);
                q1n[u] = ld2(pm1 + co + offO);
                q2n[u] = ld2(pm2 + co + offO);
            }
        }
#pragma unroll
        for (int u = 0; u < CPB; ++u) {
            float agg0 = 0.f, agg1 = 0.f;
#pragma unroll
            for (int wr = 0; wr < 3; ++wr) {
                const int r = ry + wr;
                const float Ly = s_y[base + u][r][xlh];
                float Cx, Cy;
                if (wr == 1) { Cx = cO[u].x; Cy = cO[u].y; }
                else         { Cx = s_x[base + u][r][xh]; Cy = s_y[base + u][r][xh]; }
                const float Rx = s_x[base + u][r][xrh];
                agg0 += w0[3 * wr + 0] * Ly + w0[3 * wr + 1] * Cx + w0[3 * wr + 2] * Cy;
                agg1 += w1[3 * wr + 0] * Cx + w1[3 * wr + 1] * Cy + w1[3 * wr + 2] * Rx;
            }
            const float2 ctr = cO[u];
            const float s0 = ctr.x + q0c[u].x + q1c[u].x + q2c[u].x;
            const float s1 = ctr.y + q0c[u].y + q1c[u].y + q2c[u].y;
            const float dd0 = ctr.x - 0.25f * s0;
            const float dd1 = ctr.y - 0.25f * s1;
            float2 o2;
            o2.x = agg0 * __expf(-dd0 * dd0);
            o2.y = agg1 * __expf(-dd1 * dd1);
            *reinterpret_cast<float2*>(op + (size_t)(w * CPB + u) * HW_) = o2;
        }
#pragma unroll
        for (int u = 0; u < CPB; ++u) {
            cO[u] = nO[u]; cH[u] = nH[u];
            q0c[u] = q0n[u]; q1c[u] = q1n[u]; q2c[u] = q2n[u];
        }
    }
}

}  // namespace

extern "C" void kernel_launch(void* const* d_in, const int* in_sizes, int n_in,
                              void* d_out, int out_size, void* d_ws, size_t ws_size,
                              hipStream_t stream) {
    const float* nbrs = (const float*)d_in[0];
    const float* ref = (const float*)d_in[1];
    float* out = (float*)d_out;

    // slot 4 = ref copy
    copyref_kernel<<<(B_ * C_ * HW_ / 4) / 256, 256, 0, stream>>>(ref, out);

    // main: B*N*(H/4) = 512 four-row blocks of 256 threads (2 px/thread)
    localcorr_kernel<<<B_ * N_ * (H_ / ROWS), 256, 0, stream>>>(nbrs, ref, out);
}